// Round 8
// baseline (376.374 us; speedup 1.0000x reference)
//
#include <hip/hip_runtime.h>
#include <hip/hip_bf16.h>

typedef float  f32x4  __attribute__((ext_vector_type(4)));
typedef __bf16 bf16x8 __attribute__((ext_vector_type(8)));
typedef __bf16 bf16x4 __attribute__((ext_vector_type(4)));

#define D_  512
#define H_  8
#define HD_ 64
#define B_  256
#define N_  144
#define M_  (B_*N_)   // 36864

using gptr_t = const __attribute__((address_space(1))) char*;
using lptr_t = __attribute__((address_space(3))) char*;
#define GLDS16(gp, lp) __builtin_amdgcn_global_load_lds((gptr_t)(gp), (lptr_t)(lp), 16, 0, 0)
#define SBAR()   __builtin_amdgcn_s_barrier()
#define SCHEDB() __builtin_amdgcn_sched_barrier(0)

__device__ __forceinline__ void waitv4() { asm volatile("s_waitcnt vmcnt(4)" ::: "memory"); }
__device__ __forceinline__ void waitv0() { asm volatile("s_waitcnt vmcnt(0)" ::: "memory"); }
__device__ __forceinline__ void waitlg() { asm volatile("s_waitcnt lgkmcnt(0)" ::: "memory"); }

__device__ __forceinline__ bf16x8 dsr128(unsigned addr) {
    bf16x8 r;
    asm volatile("ds_read_b128 %0, %1" : "=v"(r) : "v"(addr) : "memory");
    return r;
}

// ---------------- weight prep: f32 -> bf16 ----------------
__global__ void prep_weights_kernel(const float* __restrict__ kvw,
                                    const float* __restrict__ qw,
                                    const float* __restrict__ pw,
                                    __bf16* __restrict__ kvb,
                                    __bf16* __restrict__ qb,
                                    __bf16* __restrict__ pb) {
    int idx = blockIdx.x * 256 + threadIdx.x;
    const float* s; __bf16* d; int off;
    if (idx < 131072)      { s = kvw; d = kvb; off = idx; }
    else if (idx < 196608) { s = qw;  d = qb;  off = idx - 131072; }
    else                   { s = pw;  d = pb;  off = idx - 196608; }
    f32x4 v = *(const f32x4*)(s + (size_t)off * 4);
    bf16x4 o;
    o[0] = (__bf16)v.x; o[1] = (__bf16)v.y; o[2] = (__bf16)v.z; o[3] = (__bf16)v.w;
    *(bf16x4*)(d + (size_t)off * 4) = o;
}

// ------------- activation prep: xb = bf16(x), ab = bf16(x + tf*topo) -------------
__global__ void prep_act_kernel(const float* __restrict__ x,
                                const float* __restrict__ topo,
                                const int* __restrict__ is_end,
                                __bf16* __restrict__ xb,
                                __bf16* __restrict__ ab) {
    const float tf = (is_end[0] != 0) ? 1.f : 0.f;
    const size_t total = (size_t)M_ * D_ / 8;
    for (size_t i = (size_t)blockIdx.x * 256 + threadIdx.x; i < total;
         i += (size_t)gridDim.x * 256) {
        f32x4 a0 = *(const f32x4*)(x + i * 8);
        f32x4 a1 = *(const f32x4*)(x + i * 8 + 4);
        f32x4 t0 = *(const f32x4*)(topo + i * 8);
        f32x4 t1 = *(const f32x4*)(topo + i * 8 + 4);
        bf16x8 xo, ao;
#pragma unroll
        for (int j = 0; j < 4; ++j) {
            xo[j]     = (__bf16)a0[j];
            xo[j + 4] = (__bf16)a1[j];
            ao[j]     = (__bf16)(a0[j] + tf * t0[j]);
            ao[j + 4] = (__bf16)(a1[j] + tf * t1[j]);
        }
        *(bf16x8*)(xb + i * 8) = xo;
        *(bf16x8*)(ab + i * 8) = ao;
    }
}

// ======== mm0: fused KV+Q projection, 256x256 tile, BK=64, 8-phase counted-vmcnt ========
// 8 waves (2M x 4N), 128 KiB LDS dbuf. Stage schedule per tile t's phases:
//   p0: A0(t+1)  p1: A1(t+1)  p2: B0(t+2)  p3: B1(t+2)   (1 half-tile / phase)
// Boundary s_waitcnt vmcnt(4) at each p3 validates tile t+1 (2 halves stay in flight).
// MFMA phase p: mi {2p,2p+1} x ni 0..3 x kk 0..1 (16 mfma); B-frags all read at p0.
// T2 swizzle byte^=((row&7)<<4) via pre-swizzled global source (linear LDS dest).
__global__ __launch_bounds__(512, 2) void mm0_kernel(
        const __bf16* __restrict__ ab, const __bf16* __restrict__ xb,
        const __bf16* __restrict__ kvb, const __bf16* __restrict__ qb,
        __bf16* __restrict__ kout, __bf16* __restrict__ vTout,
        __bf16* __restrict__ qout) {
    __shared__ __align__(16) char smem[131072];

    const int tid  = threadIdx.x;
    const int lane = tid & 63, wid = tid >> 6;
    const int lrow = lane & 15, lhi = lane >> 4;
    const int wm   = wid >> 2,  wn  = wid & 3;

    // XCD swizzle: 864 wg = 8 x 108; 6 n-tiles of one m-tile stay on one XCD
    const int bid = blockIdx.x;
    const int wg  = (bid & 7) * 108 + (bid >> 3);
    const int mb  = wg / 6;
    const int nb2 = wg - mb * 6;          // 0,1=K  2,3=V  4,5=Q
    const int m0  = mb * 256;

    const __bf16* Ap = (nb2 < 4) ? ab : xb;
    const __bf16* Bp = (nb2 < 4) ? (kvb + (size_t)nb2 * 256 * D_)
                                 : (qb  + (size_t)(nb2 - 4) * 256 * D_);

    const unsigned sbase = (unsigned)(uintptr_t)(lptr_t)smem;
    const unsigned swz   = (unsigned)((lrow & 7) << 4);
    const unsigned cb0   = (0u * 64 + lhi * 16) ^ swz;
    const unsigned cb1   = (1u * 64 + lhi * 16) ^ swz;

    // stage one 128x64 half-tile (16 KiB): mat 0=A 1=B, half h, K-tile kt, dbuf d
    auto stage = [&](int mat, int h, int kt, int d) {
        const char* gb = (const char*)(mat ? Bp : Ap);
        const int rowb = (mat ? 0 : m0) + h * 128;
#pragma unroll
        for (int j = 0; j < 2; ++j) {
            int c = j * 512 + tid;
            int row = c >> 3;
            int scb = ((c & 7) * 16) ^ ((row & 7) << 4);   // pre-swizzled source col
            GLDS16(gb + (size_t)(rowb + row) * (D_ * 2) + kt * 128 + scb,
                   smem + d * 65536 + mat * 32768 + h * 16384 + c * 16);
        }
    };

    f32x4 acc[8][4];
#pragma unroll
    for (int i = 0; i < 8; ++i)
#pragma unroll
        for (int j = 0; j < 4; ++j) acc[i][j] = (f32x4){0.f, 0.f, 0.f, 0.f};

    bf16x8 Bf[4][2], Af[2][2];

    auto read_a = [&](unsigned Abase, int p) {
#pragma unroll
        for (int m2 = 0; m2 < 2; ++m2) {
            unsigned r = Abase + (unsigned)(((2 * p + m2) * 16 + lrow) * 128);
            Af[m2][0] = dsr128(r + cb0);
            Af[m2][1] = dsr128(r + cb1);
        }
    };
    auto mfma_quad = [&](int p) {
        __builtin_amdgcn_s_setprio(1);
#pragma unroll
        for (int m2 = 0; m2 < 2; ++m2)
#pragma unroll
            for (int ni = 0; ni < 4; ++ni)
#pragma unroll
                for (int kk = 0; kk < 2; ++kk)
                    acc[2 * p + m2][ni] = __builtin_amdgcn_mfma_f32_16x16x32_bf16(
                        Af[m2][kk], Bf[ni][kk], acc[2 * p + m2][ni], 0, 0, 0);
        __builtin_amdgcn_s_setprio(0);
    };

    // prologue: B0(0),B1(0),A0(0),A1(0),B0(1),B1(1) -> 12 loads; keep last 4 in flight
    stage(1, 0, 0, 0); stage(1, 1, 0, 0);
    stage(0, 0, 0, 0); stage(0, 1, 0, 0);
    stage(1, 0, 1, 1); stage(1, 1, 1, 1);
    waitv4(); SCHEDB(); SBAR();

#pragma unroll 2
    for (int t = 0; t < 8; ++t) {
        const int d = t & 1;
        const unsigned bufb = sbase + (unsigned)(d * 65536);
        const unsigned Abse = bufb + (unsigned)(wm * 16384);
        const unsigned Bbse = bufb + 32768u + (unsigned)((wn >> 1) * 16384);

        // ---- phase 0: B all + A mi0,1 (12 ds_reads); stage A0(t+1) ----
#pragma unroll
        for (int ni = 0; ni < 4; ++ni) {
            unsigned r = Bbse + (unsigned)((((wn & 1) * 64 + ni * 16 + lrow)) * 128);
            Bf[ni][0] = dsr128(r + cb0);
            Bf[ni][1] = dsr128(r + cb1);
        }
        read_a(Abse, 0);
        if (t + 1 < 8) stage(0, 0, t + 1, (t + 1) & 1);
        SCHEDB(); SBAR(); waitlg(); SCHEDB();
        mfma_quad(0);
        SCHEDB(); SBAR();

        // ---- phase 1: A mi2,3; stage A1(t+1) ----
        read_a(Abse, 1);
        if (t + 1 < 8) stage(0, 1, t + 1, (t + 1) & 1);
        SCHEDB(); SBAR(); waitlg(); SCHEDB();
        mfma_quad(1);
        SCHEDB(); SBAR();

        // ---- phase 2: A mi4,5; stage B0(t+2) (same buf d: B region dead since p0) ----
        read_a(Abse, 2);
        if (t + 2 < 8) stage(1, 0, t + 2, d);
        SCHEDB(); SBAR(); waitlg(); SCHEDB();
        mfma_quad(2);
        SCHEDB(); SBAR();

        // ---- phase 3: A mi6,7; stage B1(t+2); boundary wait validates tile t+1 ----
        read_a(Abse, 3);
        if (t + 2 < 8) stage(1, 1, t + 2, d);
        SCHEDB(); SBAR(); waitlg(); SCHEDB();
        mfma_quad(3);
        SCHEDB();
        if (t < 6) waitv4();
        else if (t == 6) waitv0();
        SBAR();
    }

    // ---- epilogue ----
    if (nb2 == 2 || nb2 == 3) {
        // V-tile: bounce through LDS (stride 258 elems -> conflict-free column reads),
        // store [B,H,64,N] with lane = consecutive nn (coalesced).
        __bf16* Ct = (__bf16*)smem;
        const int CS = 258;
#pragma unroll
        for (int s = 0; s < 2; ++s) {
            if (wm == s) {
#pragma unroll
                for (int mi = 0; mi < 8; ++mi)
#pragma unroll
                    for (int reg = 0; reg < 4; ++reg) {
                        int r = mi * 16 + lhi * 4 + reg;
#pragma unroll
                        for (int ni = 0; ni < 4; ++ni)
                            Ct[r * CS + wn * 64 + ni * 16 + lrow] = (__bf16)acc[mi][ni][reg];
                    }
            }
            __syncthreads();
            for (int it = 0; it < 64; ++it) {
                int col = wid * 32 + (it >> 1);
                int m   = (it & 1) * 64 + lane;
                __bf16 v = Ct[m * CS + col];
                int mg = m0 + s * 128 + m;
                int bb2 = mg / N_, nn = mg - bb2 * N_;
                int hh = (nb2 - 2) * 4 + (col >> 6), dd = col & 63;
                vTout[(((size_t)bb2 * H_ + hh) * HD_ + dd) * N_ + nn] = v;
            }
            __syncthreads();
        }
    } else {
        __bf16* outp = (nb2 < 2) ? kout : qout;
        const int hbase = (nb2 < 2) ? nb2 * 4 : (nb2 - 4) * 4;
#pragma unroll
        for (int mi = 0; mi < 8; ++mi)
#pragma unroll
            for (int reg = 0; reg < 4; ++reg) {
                int mg = m0 + wm * 128 + mi * 16 + lhi * 4 + reg;
                int bb2 = mg / N_, nn = mg - bb2 * N_;
#pragma unroll
                for (int ni = 0; ni < 4; ++ni) {
                    int col = wn * 64 + ni * 16 + lrow;
                    int hh = hbase + (col >> 6), dd = col & 63;
                    outp[(((size_t)bb2 * H_ + hh) * N_ + nn) * HD_ + dd] =
                        (__bf16)acc[mi][ni][reg];
                }
            }
    }
}

// ---------------- mm1: out-proj, R7 2-phase 128x128 (unchanged) ----------------
__global__ __launch_bounds__(256, 3) void mm1_kernel(
        const __bf16* __restrict__ abuf, const __bf16* __restrict__ pwb,
        const float* __restrict__ bias, float* __restrict__ pout) {
    __shared__ __align__(16) char smem[32768];
    __bf16* As = (__bf16*)smem;
    __bf16* Bs = (__bf16*)(smem + 16384);

    const int tid  = threadIdx.x;
    const int lane = tid & 63, wid = tid >> 6;
    const int lrow = lane & 15, lhi = lane >> 4;
    const int wr   = wid >> 1,  wc  = wid & 1;

    const int bid = blockIdx.x;
    const int wg  = (bid & 7) * 144 + (bid >> 3);
    const int mb  = wg / 4;
    const int nb  = wg - mb * 4;
    const int m0  = mb * 128;

    const __bf16* Ap = abuf;
    const __bf16* Bp = pwb + (size_t)nb * 128 * D_;

    f32x4 acc[4][4];
#pragma unroll
    for (int i = 0; i < 4; ++i)
#pragma unroll
        for (int j = 0; j < 4; ++j) acc[i][j] = (f32x4){0.f, 0.f, 0.f, 0.f};

    const int srow = lane >> 3;
    const int scol = (lane & 7) * 16;

    for (int kt = 0; kt < 8; ++kt) {
        const int k0 = kt * 64;
        const char* Agb = (const char*)(Ap + (size_t)m0 * D_ + k0);
        const char* Bgb = (const char*)(Bp + k0);
#pragma unroll
        for (int j = 0; j < 4; ++j) {
            const int chunk = wid * 4 + j;
            const int row   = chunk * 8 + srow;
            GLDS16(Agb + (size_t)row * (D_ * 2) + scol, (char*)As + chunk * 1024);
            GLDS16(Bgb + (size_t)row * (D_ * 2) + scol, (char*)Bs + chunk * 1024);
        }
        __syncthreads();
#pragma unroll
        for (int kk = 0; kk < 2; ++kk) {
            bf16x8 af[4], bfr[4];
#pragma unroll
            for (int mi = 0; mi < 4; ++mi)
                af[mi] = *(const bf16x8*)((const char*)As +
                          (wr * 64 + mi * 16 + lrow) * 128 + kk * 64 + lhi * 16);
#pragma unroll
            for (int ni = 0; ni < 4; ++ni)
                bfr[ni] = *(const bf16x8*)((const char*)Bs +
                          (wc * 64 + ni * 16 + lrow) * 128 + kk * 64 + lhi * 16);
#pragma unroll
            for (int mi = 0; mi < 4; ++mi)
#pragma unroll
                for (int ni = 0; ni < 4; ++ni)
                    acc[mi][ni] = __builtin_amdgcn_mfma_f32_16x16x32_bf16(
                        af[mi], bfr[ni], acc[mi][ni], 0, 0, 0);
        }
        __syncthreads();
    }

    float bv4[4];
#pragma unroll
    for (int ni = 0; ni < 4; ++ni) bv4[ni] = bias[nb * 128 + wc * 64 + ni * 16 + lrow];
#pragma unroll
    for (int mi = 0; mi < 4; ++mi)
#pragma unroll
        for (int reg = 0; reg < 4; ++reg) {
            int m = m0 + wr * 64 + mi * 16 + lhi * 4 + reg;
#pragma unroll
            for (int ni = 0; ni < 4; ++ni)
                pout[(size_t)m * D_ + nb * 128 + wc * 64 + ni * 16 + lrow] =
                    acc[mi][ni][reg] + bv4[ni];
        }
}

// ---------------- attention: one block per (b,h) (R7 version, unchanged) ----------
__launch_bounds__(256, 2)
__global__ void attn_kernel(const __bf16* __restrict__ qbuf,
                            const __bf16* __restrict__ kbuf,
                            const __bf16* __restrict__ vTbuf,
                            __bf16* __restrict__ aout) {
    __shared__ __bf16 Ks[144][72];
    __shared__ __bf16 Vs[64][168];
    __shared__ __bf16 Ps[4][16][160];

    const int tid  = threadIdx.x;
    const int lane = tid & 63, wid = tid >> 6;
    const int lrow = lane & 15, lhi = lane >> 4;
    const int bh = blockIdx.x;
    const int bb = bh >> 3, hh = bh & 7;

    const __bf16* kg = kbuf  + (size_t)bh * (N_ * HD_);
    const __bf16* vg = vTbuf + (size_t)bh * (N_ * HD_);
    const __bf16* qg = qbuf  + (size_t)bh * (N_ * HD_);

    for (int c = tid; c < 1152; c += 256) {
        int row = c >> 3, cc = c & 7;
        *(bf16x8*)&Ks[row][cc * 8] = *(const bf16x8*)(kg + row * 64 + cc * 8);
    }
    for (int c = tid; c < 1152; c += 256) {
        int dd = c / 18, cc = c - dd * 18;
        *(bf16x8*)&Vs[dd][cc * 8] = *(const bf16x8*)(vg + dd * 144 + cc * 8);
    }
    bf16x8 z8;
#pragma unroll
    for (int i = 0; i < 8; ++i) z8[i] = (__bf16)0.f;
    if (tid < 192) {
        int dd = tid / 3, cc = tid - dd * 3;
        *(bf16x8*)&Vs[dd][144 + cc * 8] = z8;
    }
    if (lhi < 2)
        *(bf16x8*)&Ps[wid][lrow][144 + lhi * 8] = z8;
    __syncthreads();

    const float sc = 0.125f * 1.44269504089f;

    for (int t = wid; t < 9; t += 4) {
        bf16x8 aq[2];
#pragma unroll
        for (int kk = 0; kk < 2; ++kk)
            aq[kk] = *(const bf16x8*)(qg + (t * 16 + lrow) * 64 + kk * 32 + lhi * 8);

        f32x4 s[9];
#pragma unroll
        for (int j = 0; j < 9; ++j) s[j] = (f32x4){0.f, 0.f, 0.f, 0.f};
#pragma unroll
        for (int j = 0; j < 9; ++j)
#pragma unroll
            for (int kk = 0; kk < 2; ++kk)
                s[j] = __builtin_amdgcn_mfma_f32_16x16x32_bf16(
                    aq[kk], *(const bf16x8*)&Ks[j * 16 + lrow][kk * 32 + lhi * 8], s[j], 0, 0, 0);

        float inv[4];
#pragma unroll
        for (int reg = 0; reg < 4; ++reg) {
            float mx = s[0][reg];
#pragma unroll
            for (int j = 1; j < 9; ++j) mx = fmaxf(mx, s[j][reg]);
#pragma unroll
            for (int off = 1; off < 16; off <<= 1) mx = fmaxf(mx, __shfl_xor(mx, off, 16));
            float sum = 0.f;
#pragma unroll
            for (int j = 0; j < 9; ++j) {
                float p = exp2f((s[j][reg] - mx) * sc);
                s[j][reg] = p;
                sum += p;
            }
#pragma unroll
            for (int off = 1; off < 16; off <<= 1) sum += __shfl_xor(sum, off, 16);
            inv[reg] = 1.f / sum;
        }
#pragma unroll
        for (int j = 0; j < 9; ++j)
#pragma unroll
            for (int reg = 0; reg < 4; ++reg)
                Ps[wid][lhi * 4 + reg][j * 16 + lrow] = (__bf16)(s[j][reg] * inv[reg]);

#pragma unroll
        for (int dc = 0; dc < 4; ++dc) {
            f32x4 o4 = (f32x4){0.f, 0.f, 0.f, 0.f};
#pragma unroll
            for (int kc = 0; kc < 5; ++kc)
                o4 = __builtin_amdgcn_mfma_f32_16x16x32_bf16(
                    *(const bf16x8*)&Ps[wid][lrow][kc * 32 + lhi * 8],
                    *(const bf16x8*)&Vs[dc * 16 + lrow][kc * 32 + lhi * 8], o4, 0, 0, 0);
#pragma unroll
            for (int reg = 0; reg < 4; ++reg) {
                int nn = t * 16 + lhi * 4 + reg;
                int dd = dc * 16 + lrow;
                aout[((size_t)bb * N_ + nn) * D_ + hh * HD_ + dd] = (__bf16)o4[reg];
            }
        }
    }
}

extern "C" void kernel_launch(void* const* d_in, const int* in_sizes, int n_in,
                              void* d_out, int out_size, void* d_ws, size_t ws_size,
                              hipStream_t stream) {
    const float* x      = (const float*)d_in[0];
    const float* topo   = (const float*)d_in[1];
    const float* kvw    = (const float*)d_in[2];
    const float* qw     = (const float*)d_in[3];
    const float* pw     = (const float*)d_in[4];
    const float* pb     = (const float*)d_in[5];
    const int*   is_end = (const int*)d_in[6];
    float* out = (float*)d_out;

    char* ws = (char*)d_ws;
    __bf16* kvb = (__bf16*)(ws);                       // 1 MiB
    __bf16* qb  = (__bf16*)(ws + (1u << 20));          // 512 KiB
    __bf16* pwb = (__bf16*)(ws + (1u << 20) + 524288); // 512 KiB
    size_t off = (1u << 20) + 2 * 524288;
    const size_t BUF = (size_t)M_ * D_ * 2;            // 37748736 B each
    __bf16* xb    = (__bf16*)(ws + off); off += BUF;   // bf16(x); reused as abuf later
    __bf16* ab    = (__bf16*)(ws + off); off += BUF;   // bf16(x + tf*topo)
    __bf16* kbuf  = (__bf16*)(ws + off); off += BUF;
    __bf16* vTbuf = (__bf16*)(ws + off); off += BUF;
    __bf16* qbuf  = (__bf16*)(ws + off); off += BUF;
    __bf16* abuf  = xb;   // xb dead after mm0; alias to stay within ws

    prep_weights_kernel<<<1024, 256, 0, stream>>>(kvw, qw, pw, kvb, qb, pwb);
    prep_act_kernel<<<2048, 256, 0, stream>>>(x, topo, is_end, xb, ab);
    mm0_kernel<<<864, 512, 0, stream>>>(ab, xb, kvb, qb, kbuf, vTbuf, qbuf);
    attn_kernel<<<2048, 256, 0, stream>>>(qbuf, kbuf, vTbuf, abuf);
    mm1_kernel<<<1152, 256, 0, stream>>>(abuf, pwb, pb, out);
}